// Round 14
// baseline (1795.404 us; speedup 1.0000x reference)
//
#include <hip/hip_runtime.h>
#include <hip/hip_bf16.h>

#define V_N   150000
#define NCAMS 6
#define DINO  384
#define HFEAT 64
#define WFEAT 112
#define PTV3  16
#define HID   128
#define NCLS  32
#define HBEV  200
#define WBEV  200
#define NCELL (HBEV*WBEV)

__device__ __forceinline__ float bf2f(unsigned int u) {
    return __uint_as_float(u << 16);
}
__device__ __forceinline__ unsigned short f2bf(float f) {
    unsigned int x = __float_as_uint(f);
    unsigned int r = (x + 0x7fffu + ((x >> 16) & 1u)) >> 16;
    return (unsigned short)r;
}

// ---------------------------------------------------------------- K0: (6,384,64,112) f32 -> (6,64,112,384) bf16
__global__ __launch_bounds__(256) void k0_transpose(const float* __restrict__ src,
                                                    unsigned short* __restrict__ dst) {
    __shared__ float tile[32][33];
    int camy = blockIdx.z;              // cam*64 + y
    int cam = camy >> 6, y = camy & 63;
    int X0 = blockIdx.x * 32, C0 = blockIdx.y * 32;
    int tx = threadIdx.x, ty = threadIdx.y;   // 32 x 8
#pragma unroll
    for (int i = 0; i < 4; i++) {
        int c = C0 + ty + i * 8;
        int x = X0 + tx;
        float v = 0.f;
        if (x < WFEAT) v = src[(((size_t)cam * DINO + c) * HFEAT + y) * WFEAT + x];
        tile[ty + i * 8][tx] = v;
    }
    __syncthreads();
#pragma unroll
    for (int i = 0; i < 4; i++) {
        int x = X0 + ty + i * 8;
        int c = C0 + tx;
        if (x < WFEAT)
            dst[(((size_t)cam * HFEAT + y) * WFEAT + x) * DINO + c] = f2bf(tile[tx][ty + i * 8]);
    }
}

// ---------------------------------------------------------------- K1: projection + bilinear + LN -> vis_ln chunk (bf16)
__global__ __launch_bounds__(128) void k1_project(
    const unsigned short* __restrict__ featT, const float* __restrict__ coords,
    const float* __restrict__ calib, const int* __restrict__ himgp,
    const int* __restrict__ wimgp, const float* __restrict__ lng,
    const float* __restrict__ lnb, unsigned short* __restrict__ visln,
    int vbase) {
    __shared__ int   sMask[NCAMS], sX0[NCAMS], sY0[NCAMS];
    __shared__ float sWx[NCAMS], sWy[NCAMS];
    __shared__ float sS[2], sQ[2];
    int lv = blockIdx.x;          // chunk-local row
    int v = vbase + lv;           // global voxel
    int t = threadIdx.x;
    if (t < NCAMS) {
        float x = coords[v * 3 + 0], y = coords[v * 3 + 1], z = coords[v * 3 + 2];
        const float* c = calib + t * 12;
        float p0 = c[0] * x + c[1] * y + c[2] * z + c[3];
        float p1 = c[4] * x + c[5] * y + c[6] * z + c[7];
        float w  = c[8] * x + c[9] * y + c[10] * z + c[11];
        float wim = (float)wimgp[0], him = (float)himgp[0];
        float mw = fmaxf(w, 1e-6f);
        float u = p0 / mw, vv = p1 / mw;
        int m = (w > 0.f) && (u >= 0.f) && (u < wim) && (vv >= 0.f) && (vv < him);
        float xs = u * (float)(WFEAT - 1) / wim;
        float ys = vv * (float)(HFEAT - 1) / him;
        float x0f = floorf(xs), y0f = floorf(ys);
        sMask[t] = m;
        sX0[t] = (int)x0f;
        sY0[t] = (int)y0f;
        sWx[t] = xs - x0f;
        sWy[t] = ys - y0f;
    }
    __syncthreads();
    float acc0 = 0.f, acc1 = 0.f, acc2 = 0.f;
    int cnt = 0;
#pragma unroll
    for (int cam = 0; cam < NCAMS; cam++) {
        if (sMask[cam]) {
            cnt++;
            int x0 = min(max(sX0[cam], 0), WFEAT - 1);
            int y0 = min(max(sY0[cam], 0), HFEAT - 1);
            int x1 = min(x0 + 1, WFEAT - 1);
            int y1 = min(y0 + 1, HFEAT - 1);
            float wx = sWx[cam], wy = sWy[cam];
            float w00 = (1.f - wx) * (1.f - wy), w01 = wx * (1.f - wy);
            float w10 = (1.f - wx) * wy,        w11 = wx * wy;
            const unsigned short* b00 = featT + (((size_t)cam * HFEAT + y0) * WFEAT + x0) * DINO;
            const unsigned short* b01 = featT + (((size_t)cam * HFEAT + y0) * WFEAT + x1) * DINO;
            const unsigned short* b10 = featT + (((size_t)cam * HFEAT + y1) * WFEAT + x0) * DINO;
            const unsigned short* b11 = featT + (((size_t)cam * HFEAT + y1) * WFEAT + x1) * DINO;
            acc0 += w00 * bf2f(b00[t])       + w01 * bf2f(b01[t])       + w10 * bf2f(b10[t])       + w11 * bf2f(b11[t]);
            acc1 += w00 * bf2f(b00[t + 128]) + w01 * bf2f(b01[t + 128]) + w10 * bf2f(b10[t + 128]) + w11 * bf2f(b11[t + 128]);
            acc2 += w00 * bf2f(b00[t + 256]) + w01 * bf2f(b01[t + 256]) + w10 * bf2f(b10[t + 256]) + w11 * bf2f(b11[t + 256]);
        }
    }
    float inv = cnt > 0 ? 1.f / (float)cnt : 1.f;
    acc0 *= inv; acc1 *= inv; acc2 *= inv;
    float s = acc0 + acc1 + acc2;
    float q = acc0 * acc0 + acc1 * acc1 + acc2 * acc2;
#pragma unroll
    for (int off = 32; off >= 1; off >>= 1) {
        s += __shfl_xor(s, off);
        q += __shfl_xor(q, off);
    }
    int wid = t >> 6;
    if ((t & 63) == 0) { sS[wid] = s; sQ[wid] = q; }
    __syncthreads();
    s = sS[0] + sS[1];
    q = sQ[0] + sQ[1];
    float mean = s * (1.f / DINO);
    float var = q * (1.f / DINO) - mean * mean;
    float r = rsqrtf(var + 1e-5f);
    size_t base = (size_t)lv * DINO;
    visln[base + t]       = f2bf((acc0 - mean) * r * lng[t]       + lnb[t]);
    visln[base + t + 128] = f2bf((acc1 - mean) * r * lng[t + 128] + lnb[t + 128]);
    visln[base + t + 256] = f2bf((acc2 - mean) * r * lng[t + 256] + lnb[t + 256]);
}

// ---------------------------------------------------------------- K2: embeddings + gate + fused + BEV scatter (chunked)
__global__ __launch_bounds__(256) void k2_embed(
    const float* __restrict__ pf, const unsigned short* __restrict__ visln,
    const float* __restrict__ coords,
    const float* __restrict__ l_g, const float* __restrict__ l_b,
    const float* __restrict__ l_w, const float* __restrict__ l_bias,
    const float* __restrict__ i_w, const float* __restrict__ i_bias,
    const float* __restrict__ g_w1, const float* __restrict__ g_b1,
    const float* __restrict__ g_w2, const float* __restrict__ g_b2,
    unsigned short* __restrict__ fusedB, int* __restrict__ idxG,
    float* __restrict__ bevI, float* __restrict__ bevF,
    unsigned int* __restrict__ cntG, int vbase, int vEnd) {
    __shared__ alignas(16) float sA[32 * 64];
    __shared__ alignas(16) float sLid[32 * HID];
    __shared__ alignas(16) float sImg[32 * HID];
    __shared__ alignas(16) float sLn16[32 * 16];
    __shared__ float sRed[4 * 16];
    __shared__ float sGate[32];
    __shared__ int   sIdx[32];

    int tid = threadIdx.x;
    int h = tid & 127, half = tid >> 7;
    int v0 = vbase + blockIdx.x * 32;

    // ---- phase 1: lidar LN (threads 0..31, one voxel each)
    if (tid < 32) {
        int gv = v0 + tid;
        if (gv < vEnd) {
            float x[16];
#pragma unroll
            for (int k = 0; k < 16; k++) x[k] = pf[(size_t)gv * 16 + k];
            float s = 0.f;
#pragma unroll
            for (int k = 0; k < 16; k++) s += x[k];
            float m = s * (1.f / 16.f);
            float q = 0.f;
#pragma unroll
            for (int k = 0; k < 16; k++) { float d = x[k] - m; q += d * d; }
            float r = rsqrtf(q * (1.f / 16.f) + 1e-5f);
#pragma unroll
            for (int k = 0; k < 16; k++)
                sLn16[tid * 16 + k] = (x[k] - m) * r * l_g[k] + l_b[k];
        } else {
#pragma unroll
            for (int k = 0; k < 16; k++) sLn16[tid * 16 + k] = 0.f;
        }
    }
    __syncthreads();

    // ---- phase 2: lidar embedding
    {
        float wreg[16];
#pragma unroll
        for (int k = 0; k < 16; k++) wreg[k] = l_w[k * HID + h];
        float bb = l_bias[h];
#pragma unroll
        for (int v = 0; v < 16; v++) {
            int vv = half * 16 + v;
            float a = bb;
#pragma unroll
            for (int k = 0; k < 16; k++) a += sLn16[vv * 16 + k] * wreg[k];
            sLid[vv * HID + h] = fmaxf(a, 0.f);
        }
    }

    // ---- phase 3: img GEMM  relu(vis_ln @ (384x128) + b)
    float accI[16];
    {
        float bb = i_bias[h];
#pragma unroll
        for (int v = 0; v < 16; v++) accI[v] = bb;
    }
    for (int kc = 0; kc < 6; kc++) {
        __syncthreads();
        {
            int row = tid >> 3, col8 = (tid & 7) * 8;
            int gv = v0 + row;
            uint4 raw = make_uint4(0u, 0u, 0u, 0u);
            if (gv < vEnd)
                raw = *reinterpret_cast<const uint4*>(visln + (size_t)(gv - vbase) * DINO + kc * 64 + col8);
            float* d = &sA[row * 64 + col8];
            d[0] = bf2f(raw.x & 0xffffu); d[1] = bf2f(raw.x >> 16);
            d[2] = bf2f(raw.y & 0xffffu); d[3] = bf2f(raw.y >> 16);
            d[4] = bf2f(raw.z & 0xffffu); d[5] = bf2f(raw.z >> 16);
            d[6] = bf2f(raw.w & 0xffffu); d[7] = bf2f(raw.w >> 16);
        }
        __syncthreads();
        const float* wp = i_w + (size_t)(kc * 64) * HID + h;
#pragma unroll 4
        for (int k4 = 0; k4 < 16; k4++) {
            float w0 = wp[(k4 * 4 + 0) * HID];
            float w1 = wp[(k4 * 4 + 1) * HID];
            float w2 = wp[(k4 * 4 + 2) * HID];
            float w3 = wp[(k4 * 4 + 3) * HID];
#pragma unroll
            for (int v = 0; v < 16; v++) {
                int vv = half * 16 + v;
                float4 a = *reinterpret_cast<const float4*>(&sA[vv * 64 + k4 * 4]);
                accI[v] += a.x * w0 + a.y * w1 + a.z * w2 + a.w * w3;
            }
        }
    }
#pragma unroll
    for (int v = 0; v < 16; v++) {
        accI[v] = fmaxf(accI[v], 0.f);
        sImg[(half * 16 + v) * HID + h] = accI[v];
    }
    __syncthreads();

    // ---- phase 4: gate hidden
    float hv[16];
    {
        float accG[16];
        float bb = g_b1[h];
#pragma unroll
        for (int v = 0; v < 16; v++) accG[v] = bb;
        const float* wl = g_w1 + h;
#pragma unroll 4
        for (int k4 = 0; k4 < 32; k4++) {
            float w0 = wl[(k4 * 4 + 0) * HID];
            float w1 = wl[(k4 * 4 + 1) * HID];
            float w2 = wl[(k4 * 4 + 2) * HID];
            float w3 = wl[(k4 * 4 + 3) * HID];
#pragma unroll
            for (int v = 0; v < 16; v++) {
                float4 a = *reinterpret_cast<const float4*>(&sLid[(half * 16 + v) * HID + k4 * 4]);
                accG[v] += a.x * w0 + a.y * w1 + a.z * w2 + a.w * w3;
            }
        }
        const float* wi = g_w1 + (size_t)128 * HID + h;
#pragma unroll 4
        for (int k4 = 0; k4 < 32; k4++) {
            float w0 = wi[(k4 * 4 + 0) * HID];
            float w1 = wi[(k4 * 4 + 1) * HID];
            float w2 = wi[(k4 * 4 + 2) * HID];
            float w3 = wi[(k4 * 4 + 3) * HID];
#pragma unroll
            for (int v = 0; v < 16; v++) {
                float4 a = *reinterpret_cast<const float4*>(&sImg[(half * 16 + v) * HID + k4 * 4]);
                accG[v] += a.x * w0 + a.y * w1 + a.z * w2 + a.w * w3;
            }
        }
#pragma unroll
        for (int v = 0; v < 16; v++) hv[v] = fmaxf(accG[v], 0.f);
    }

    // ---- phase 5: gate scalar
    {
        float w2h = g_w2[h];
        int lane = tid & 63, wid = tid >> 6;
#pragma unroll
        for (int v = 0; v < 16; v++) {
            float p = hv[v] * w2h;
#pragma unroll
            for (int off = 32; off >= 1; off >>= 1) p += __shfl_xor(p, off);
            if (lane == 0) sRed[wid * 16 + v] = p;
        }
    }
    __syncthreads();
    if (tid < 32) {
        int hf = tid >> 4, vi = tid & 15;
        float s = sRed[(hf * 2) * 16 + vi] + sRed[(hf * 2 + 1) * 16 + vi] + g_b2[0];
        sGate[tid] = 1.f / (1.f + expf(-s));
        int gv = v0 + tid;
        int id = -1;
        if (gv < vEnd) {
            float x = coords[gv * 3 + 0], y = coords[gv * 3 + 1];
            int ix = (int)floorf((x + 50.f) * 2.f);
            int iy = (int)floorf((y + 50.f) * 2.f);
            if (ix >= 0 && ix < WBEV && iy >= 0 && iy < HBEV) id = iy * WBEV + ix;
            idxG[gv] = id;
            if (id >= 0) atomicAdd(&cntG[id], 1u);
        }
        sIdx[tid] = id;
    }
    __syncthreads();

    // ---- phase 6: fused combine + scatter
#pragma unroll
    for (int v = 0; v < 16; v++) {
        int vv = half * 16 + v;
        int gv = v0 + vv;
        if (gv < vEnd) {
            float g = sGate[vv];
            float im = sImg[vv * HID + h], li = sLid[vv * HID + h];
            float f = g * im + (1.f - g) * li;
            fusedB[(size_t)gv * HID + h] = f2bf(f);
            int id = sIdx[vv];
            if (id >= 0) {
                atomicAdd(&bevF[(size_t)id * HID + h], f);
                atomicAdd(&bevI[(size_t)id * HID + h], im);
            }
        }
    }
}

// ---------------------------------------------------------------- K3: BEV means (lidRows in-place over bevF)
__global__ __launch_bounds__(256) void k3_means(const float* __restrict__ bevI,
                                                float* __restrict__ bevF,
                                                const unsigned int* __restrict__ cnt,
                                                float* __restrict__ imgPlanar) {
    int tid = blockIdx.x * 256 + threadIdx.x;
    if (tid >= NCELL * HID) return;
    int cell = tid >> 7, ch = tid & 127;
    unsigned int c = cnt[cell];
    float inv = c ? 1.f / (float)c : 1.f;
    bevF[tid] = bevF[tid] * inv;
    imgPlanar[(size_t)ch * NCELL + cell] = bevI[tid] * inv;
}

// ---------------------------------------------------------------- conv 3x3 (SAME), 128->128, 200x200
template <int RELU, int OUT_PLANAR>
__global__ __launch_bounds__(256) void kconv(const float* __restrict__ in,
                                             const float* __restrict__ w,
                                             const float* __restrict__ bias,
                                             float* __restrict__ out) {
    __shared__ alignas(16) float sIn[8 * 10 * 40];
    __shared__ alignas(16) float sW[8 * 9 * 16];
    int tid = threadIdx.x;
    int X0 = blockIdx.x * 32, Y0 = blockIdx.y * 8, OC0 = blockIdx.z * 16;
    int ocg = tid >> 6, yy = (tid >> 3) & 7, xg = tid & 7;
    float acc[4][4];
#pragma unroll
    for (int p = 0; p < 4; p++)
#pragma unroll
        for (int o = 0; o < 4; o++) acc[p][o] = 0.f;

    for (int icc = 0; icc < 16; icc++) {
        __syncthreads();
        for (int j = tid; j < 8 * 10 * 34; j += 256) {
            int xx = j % 34;
            int r = j / 34;
            int yyi = r % 10;
            int ic = r / 10;
            int gx = X0 - 1 + xx, gy = Y0 - 1 + yyi;
            float v = 0.f;
            if (gx >= 0 && gx < WBEV && gy >= 0 && gy < HBEV)
                v = in[(size_t)(icc * 8 + ic) * NCELL + gy * WBEV + gx];
            sIn[(ic * 10 + yyi) * 40 + xx] = v;
        }
        for (int j = tid; j < 8 * 9 * 16; j += 256) {
            int o = j & 15;
            int r = j >> 4;
            int tap = r % 9;
            int ic = r / 9;
            sW[(ic * 9 + tap) * 16 + o] = w[((size_t)(OC0 + o) * HID + icc * 8 + ic) * 9 + tap];
        }
        __syncthreads();
#pragma unroll
        for (int ic = 0; ic < 8; ic++) {
#pragma unroll
            for (int dy = 0; dy < 3; dy++) {
                const float* rowp = &sIn[(ic * 10 + yy + dy) * 40 + xg * 4];
                float4 lo = *reinterpret_cast<const float4*>(rowp);
                float2 hi = *reinterpret_cast<const float2*>(rowp + 4);
                float a[6] = {lo.x, lo.y, lo.z, lo.w, hi.x, hi.y};
#pragma unroll
                for (int dx = 0; dx < 3; dx++) {
                    float4 wv = *reinterpret_cast<const float4*>(&sW[(ic * 9 + dy * 3 + dx) * 16 + ocg * 4]);
#pragma unroll
                    for (int p = 0; p < 4; p++) {
                        float av = a[p + dx];
                        acc[p][0] += av * wv.x;
                        acc[p][1] += av * wv.y;
                        acc[p][2] += av * wv.z;
                        acc[p][3] += av * wv.w;
                    }
                }
            }
        }
    }
    int y = Y0 + yy;
#pragma unroll
    for (int p = 0; p < 4; p++) {
        int x = X0 + xg * 4 + p;
        if (x < WBEV) {
#pragma unroll
            for (int o = 0; o < 4; o++) {
                int oc = OC0 + ocg * 4 + o;
                float vv = acc[p][o] + bias[oc];
                if (RELU) vv = fmaxf(vv, 0.f);
                if (OUT_PLANAR)
                    out[(size_t)oc * NCELL + y * WBEV + x] = vv;
                else
                    out[(size_t)(y * WBEV + x) * HID + oc] = vv;
            }
        }
    }
}

// ---------------------------------------------------------------- K6: gather + LN + seg head -> f32 out
__global__ __launch_bounds__(128) void k6_final(
    const unsigned short* __restrict__ fusedB, const int* __restrict__ idxG,
    const float* __restrict__ lidRows, const float* __restrict__ c2out,
    const float* __restrict__ alphap, const float* __restrict__ og,
    const float* __restrict__ ob, const float* __restrict__ segw,
    const float* __restrict__ segb, float* __restrict__ outp) {
    __shared__ alignas(16) float sLn[HID];
    __shared__ float sS[2], sQ[2];
    int v = blockIdx.x, t = threadIdx.x;
    float f = bf2f(fusedB[(size_t)v * HID + t]);
    int id = idxG[v];
    float alpha = fminf(fmaxf(alphap[0], 0.f), 1.f);
    if (id >= 0)
        f += alpha * (lidRows[(size_t)id * HID + t] + 0.5f * c2out[(size_t)id * HID + t]);
    float s = f, q = f * f;
#pragma unroll
    for (int off = 32; off >= 1; off >>= 1) {
        s += __shfl_xor(s, off);
        q += __shfl_xor(q, off);
    }
    int wid = t >> 6;
    if ((t & 63) == 0) { sS[wid] = s; sQ[wid] = q; }
    __syncthreads();
    s = sS[0] + sS[1];
    q = sQ[0] + sQ[1];
    float m = s * (1.f / HID);
    float var = q * (1.f / HID) - m * m;
    float r = rsqrtf(var + 1e-5f);
    sLn[t] = (f - m) * r * og[t] + ob[t];
    __syncthreads();
    if (t < NCLS) {
        float a = segb[t];
#pragma unroll 8
        for (int k = 0; k < HID; k++) a += sLn[k] * segw[k * NCLS + t];
        outp[(size_t)v * NCLS + t] = a;   // f32 output (reference dtype)
    }
}

// ----------------------------------------------------------------
extern "C" void kernel_launch(void* const* d_in, const int* in_sizes, int n_in,
                              void* d_out, int out_size, void* d_ws, size_t ws_size,
                              hipStream_t stream) {
    const float* pf      = (const float*)d_in[0];
    const float* imgfeat = (const float*)d_in[1];
    const float* coords  = (const float*)d_in[2];
    const float* calib   = (const float*)d_in[3];
    const float* l_g     = (const float*)d_in[4];
    const float* l_b     = (const float*)d_in[5];
    const float* l_w     = (const float*)d_in[6];
    const float* l_bias  = (const float*)d_in[7];
    const float* i_g     = (const float*)d_in[8];
    const float* i_b     = (const float*)d_in[9];
    const float* i_w     = (const float*)d_in[10];
    const float* i_bias  = (const float*)d_in[11];
    const float* g_w1    = (const float*)d_in[12];
    const float* g_b1    = (const float*)d_in[13];
    const float* g_w2    = (const float*)d_in[14];
    const float* g_b2    = (const float*)d_in[15];
    const float* c1w     = (const float*)d_in[16];
    const float* c1b     = (const float*)d_in[17];
    const float* c2w     = (const float*)d_in[18];
    const float* c2b     = (const float*)d_in[19];
    const float* alphap  = (const float*)d_in[20];
    const float* o_g     = (const float*)d_in[21];
    const float* o_b     = (const float*)d_in[22];
    const float* segw    = (const float*)d_in[23];
    const float* segb    = (const float*)d_in[24];
    const int*   himg    = (const int*)d_in[25];
    const int*   wimg    = (const int*)d_in[26];

    char* ws = (char*)d_ws;
    size_t off = 0;
    auto alloc = [&](size_t bytes) -> void* {
        void* p = ws + off;
        off = (off + bytes + 255) & ~(size_t)255;
        return p;
    };
    // ---- fixed allocations (~133.4 MB)
    unsigned short* featT  = (unsigned short*)alloc(sizeof(unsigned short) * (size_t)NCAMS * HFEAT * WFEAT * DINO); // 33.0 MB
    unsigned short* fusedB = (unsigned short*)alloc(sizeof(unsigned short) * (size_t)V_N * HID);                    // 38.4 MB
    float*          bevI   = (float*)alloc(sizeof(float) * (size_t)NCELL * HID);                                    // 20.5 MB
    float*          bevF   = (float*)alloc(sizeof(float) * (size_t)NCELL * HID);                                    // 20.5 MB (-> lidRows)
    float*          hb     = (float*)alloc(sizeof(float) * (size_t)NCELL * HID);                                    // 20.5 MB
    unsigned int*   cntG   = (unsigned int*)alloc(sizeof(unsigned int) * (size_t)NCELL);                            // 0.16 MB
    int*            idxG   = (int*)alloc(sizeof(int) * (size_t)V_N);                                                // 0.6 MB
    // ---- vis_ln chunk buffer takes remaining workspace (adaptive)
    size_t remain = (ws_size > off + 256) ? (ws_size - off - 256) : 0;
    long long rows = (long long)(remain / (sizeof(unsigned short) * DINO));
    if (rows > V_N) rows = V_N;
    rows &= ~31LL;                       // multiple of 32 (k2 block granularity)
    if (rows < 32) rows = 32;            // floor; below this ws is unusable anyway
    int chunkRows = (int)rows;
    unsigned short* vislnC = (unsigned short*)alloc(sizeof(unsigned short) * (size_t)chunkRows * DINO);
    // lifetime aliases (stream order makes these safe; both regions >= 20.5 MB):
    float* imgMean = (float*)featT;      // k3 writes after featT dead
    float* c2out   = (float*)featT;      // conv2 writes after imgMean dead (conv2 reads hb only)
    (void)in_sizes; (void)n_in; (void)out_size;

    hipMemsetAsync(bevI, 0, sizeof(float) * (size_t)NCELL * HID, stream);
    hipMemsetAsync(bevF, 0, sizeof(float) * (size_t)NCELL * HID, stream);
    hipMemsetAsync(cntG, 0, sizeof(unsigned int) * (size_t)NCELL, stream);

    k0_transpose<<<dim3(4, 12, NCAMS * HFEAT), dim3(32, 8), 0, stream>>>(imgfeat, featT);

    for (int vb = 0; vb < V_N; vb += chunkRows) {
        int cnt = (V_N - vb < chunkRows) ? (V_N - vb) : chunkRows;
        k1_project<<<cnt, 128, 0, stream>>>(featT, coords, calib, himg, wimg,
                                            i_g, i_b, vislnC, vb);
        k2_embed<<<(cnt + 31) / 32, 256, 0, stream>>>(pf, vislnC, coords,
                                                      l_g, l_b, l_w, l_bias,
                                                      i_w, i_bias, g_w1, g_b1, g_w2, g_b2,
                                                      fusedB, idxG, bevI, bevF, cntG,
                                                      vb, vb + cnt);
    }

    k3_means<<<(NCELL * HID + 255) / 256, 256, 0, stream>>>(bevI, bevF, cntG, imgMean);

    kconv<1, 1><<<dim3(7, 25, 8), 256, 0, stream>>>(imgMean, c1w, c1b, hb);
    kconv<0, 0><<<dim3(7, 25, 8), 256, 0, stream>>>(hb, c2w, c2b, c2out);

    k6_final<<<V_N, 128, 0, stream>>>(fusedB, idxG, bevF /*lidRows*/, c2out, alphap, o_g, o_b,
                                      segw, segb, (float*)d_out);
}